// Round 1
// baseline (181.356 us; speedup 1.0000x reference)
//
#include <hip/hip_runtime.h>
#include <stdint.h>
#include <stddef.h>

typedef _Float16 h2 __attribute__((ext_vector_type(2)));
typedef _Float16 h8 __attribute__((ext_vector_type(8)));
typedef float f4 __attribute__((ext_vector_type(4)));

union Hfrag { h2 p[4]; h8 v; };

// generic -> addrspace casts for global_load_lds (flat LDS pointer low 32 bits = group offset)
#define AS1C(p) ((const __attribute__((address_space(1))) void*)(uintptr_t)(p))
#define AS3(p)  ((__attribute__((address_space(3))) void*)(uint32_t)(uintptr_t)(p))

// ---------------- workspace layout (bytes) ----------------
// pmin/pmax are dead after K2; Bt (built in K3) overlays them.
#define WS_PMIN   0
#define WS_PMAX   262144
#define WS_BT     0               // f16 [80 ks][2 half][128 o][32 kk] = 1,310,720 B
#define WS_SMALL  1310720
#define WS_MINV   (WS_SMALL + 0)
#define WS_SCALEV (WS_SMALL + 1024)
#define WS_RANGEV (WS_SMALL + 2048)
#define WS_BSC    (WS_SMALL + 3072)
#define WS_BSH    (WS_SMALL + 4096)   // includes folded min^T @ Wb bias
#define WS_SSC    (WS_SMALL + 5120)
#define WS_SSH    (WS_SMALL + 6144)
// total ws use: 1,317,888 B

// ---------------- K1: per-feature min/max partials ----------------
__global__ __launch_bounds__(256) void kan_minmax(const float* __restrict__ x,
                                                  float* __restrict__ pmin,
                                                  float* __restrict__ pmax) {
  const int b = blockIdx.x, f = threadIdx.x;      // 256 blocks x 128 rows
  const float* p = x + (size_t)b * 128 * 256 + f;
  float mn = 3.402823466e38f, mx = -3.402823466e38f;
#pragma unroll 8
  for (int r = 0; r < 128; ++r) {
    float v = p[(size_t)r * 256];
    mn = fminf(mn, v); mx = fmaxf(mx, v);
  }
  pmin[b * 256 + f] = mn;
  pmax[b * 256 + f] = mx;
}

// ---------------- K2: finalize minmax + constants (1 block, 256 threads) ----------------
__global__ __launch_bounds__(256) void kan_finalize(
    const float* __restrict__ pmin, const float* __restrict__ pmax,
    const float* __restrict__ base_w,
    const float* __restrict__ g1, const float* __restrict__ b1,
    const float* __restrict__ m1, const float* __restrict__ v1,
    const float* __restrict__ g2, const float* __restrict__ b2,
    const float* __restrict__ m2, const float* __restrict__ v2,
    float* __restrict__ minv, float* __restrict__ scalev, float* __restrict__ rangev,
    float* __restrict__ bscv, float* __restrict__ bshv,
    float* __restrict__ sscv, float* __restrict__ sshv) {
  __shared__ float smin[256];
  const int o = threadIdx.x;
  float mn = 3.402823466e38f, mx = -3.402823466e38f;
  for (int p = 0; p < 256; ++p) {
    mn = fminf(mn, pmin[p * 256 + o]);
    mx = fmaxf(mx, pmax[p * 256 + o]);
  }
  const float rangeE = mx - mn + 1e-7f;          // (max-min+eps), ref denominator
  minv[o] = mn; rangev[o] = rangeE; scalev[o] = 1.0f / rangeE;
  smin[o] = mn;
  __syncthreads();
  // bias c_o = sum_i min_i * Wb[i,o]  (folded into base BN shift)
  float c = 0.0f;
  for (int i = 0; i < 256; ++i) c = fmaf(smin[i], base_w[i * 256 + o], c);
  const float bs = g1[o] / sqrtf(v1[o] + 1e-3f);
  bscv[o] = bs;
  bshv[o] = b1[o] - m1[o] * bs + bs * c;
  const float ss = g2[o] / sqrtf(v2[o] + 1e-3f);
  sscv[o] = ss;
  sshv[o] = b2[o] - m2[o] * ss;
}

// ---------------- K3: build f16 weight matrix Bt ----------------
// Bt flat index f = ((ks*2 + half)*128 + o)*32 + kk
// ks<72: spline, K-index c = ks*32+kk -> k=c>>8 (knot), i=c&255; val = sw[o,i,k]*ss[o,i]
// ks>=72: base,   i = (ks-72)*32+kk;  val = Wb[i,o]*rangeE_i  (A will be xn)
__global__ __launch_bounds__(256) void kan_buildw(
    const float* __restrict__ spline_w, const float* __restrict__ spline_s,
    const float* __restrict__ base_w, const float* __restrict__ rangev,
    _Float16* __restrict__ Bt) {
  const int gid = blockIdx.x * 256 + threadIdx.x;  // 640 blocks -> 163840 threads
  const int f = gid * 4;
  const int ks = f >> 13;
  const int rem = f & 8191;
  const int half = rem >> 12;
  const int rem2 = rem & 4095;
  const int o = rem2 >> 5;
  const int kk = rem2 & 31;
  const int og = half * 128 + o;
  float v[4];
  if (ks < 72) {
    const int k = ks >> 3;
    const int i0 = ((ks & 7) << 5) + kk;
#pragma unroll
    for (int j = 0; j < 4; ++j) {
      const int i = i0 + j;
      v[j] = spline_w[(size_t)(og * 256 + i) * 9 + k] * spline_s[og * 256 + i];
    }
  } else {
    const int i0 = (ks - 72) * 32 + kk;
#pragma unroll
    for (int j = 0; j < 4; ++j) {
      const int i = i0 + j;
      v[j] = base_w[(size_t)i * 256 + og] * rangev[i];
    }
  }
  union { _Float16 h[4]; uint2 u; } pk;
#pragma unroll
  for (int j = 0; j < 4; ++j) pk.h[j] = (_Float16)v[j];
  *(uint2*)(Bt + f) = pk.u;
}

// ---------------- K4: fused dual GEMM + BN + SiLU ----------------
// 128x128 output tile, 4 waves (2x2), 16x16x32 f16 MFMA.
// A (spline basis / xn) generated in registers; B staged via global_load_lds, double-buffered.
__global__ __launch_bounds__(256, 2) void kan_gemm(
    const float* __restrict__ x, const _Float16* __restrict__ Bt,
    const float* __restrict__ minv, const float* __restrict__ scalev,
    const float* __restrict__ bscv, const float* __restrict__ bshv,
    const float* __restrict__ sscv, const float* __restrict__ sshv,
    float* __restrict__ out) {
  __shared__ __attribute__((aligned(16))) _Float16 bsm[2][4096];  // 2 x 8 KB
  const int tid = threadIdx.x;
  const int lane = tid & 63;
  const int wv = tid >> 6;
  const int wm = wv >> 1, wn = wv & 1;
  const int lr = lane & 15, lg = lane >> 4;
  const int mt = blockIdx.x & 255, nt = blockIdx.x >> 8;  // bid,bid+256 share XCD -> x L2 reuse

  const int rowA = mt * 128 + wm * 64 + lr;   // + 16*m
  const int colB = wn * 64 + lr;              // local out col; + 16*n, global +nt*128

  f4 accS[4][4], accB[4][4];
#pragma unroll
  for (int m = 0; m < 4; ++m)
#pragma unroll
    for (int n = 0; n < 4; ++n) { accS[m][n] = (f4)0.0f; accB[m][n] = (f4)0.0f; }

  const char* btb = (const char*)Bt + (size_t)nt * 8192 + (size_t)tid * 16;

  f4 xa[4], xb[4], mn0, mn1, sc0, sc1;
  Hfrag xn[4];

  { // load x fragment regs for ic=0 (+ per-feature min/scale)
    const int ib = lg * 8;
#pragma unroll
    for (int m = 0; m < 4; ++m) {
      const float* px = x + (size_t)(rowA + m * 16) * 256 + ib;
      xa[m] = *(const f4*)px; xb[m] = *(const f4*)(px + 4);
    }
    mn0 = *(const f4*)(minv + ib);  mn1 = *(const f4*)(minv + ib + 4);
    sc0 = *(const f4*)(scalev + ib); sc1 = *(const f4*)(scalev + ib + 4);
  }
  // stage first chunk: (ic=0, it=0) -> ks = 1*8+0 = 8  (knot k=0 chunks are identically zero: skipped)
  {
    char* dst = (char*)&bsm[0][0] + tid * 16;
    __builtin_amdgcn_global_load_lds(AS1C(btb + (size_t)8 * 16384), AS3(dst), 16, 0, 0);
    __builtin_amdgcn_global_load_lds(AS1C(btb + (size_t)8 * 16384 + 4096), AS3(dst + 4096), 16, 0, 0);
  }
  __syncthreads();

  int buf = 0;
  for (int ic = 0; ic < 8; ++ic) {
    // xn = (x - min) * scale, packed f16 pairs (A-fragment layout)
#pragma unroll
    for (int m = 0; m < 4; ++m) {
      f4 na = (xa[m] - mn0) * sc0;
      f4 nb = (xb[m] - mn1) * sc1;
      xn[m].p[0][0] = (_Float16)na.x; xn[m].p[0][1] = (_Float16)na.y;
      xn[m].p[1][0] = (_Float16)na.z; xn[m].p[1][1] = (_Float16)na.w;
      xn[m].p[2][0] = (_Float16)nb.x; xn[m].p[2][1] = (_Float16)nb.y;
      xn[m].p[3][0] = (_Float16)nb.z; xn[m].p[3][1] = (_Float16)nb.w;
    }
#pragma unroll
    for (int it = 0; it < 9; ++it) {   // it 0..7: knots 1..8 ; it 8: base GEMM step
      if (!(ic == 7 && it == 8)) {     // stage next chunk into other buffer
        const int nks = (it < 7) ? ((it + 2) * 8 + ic) : ((it == 7) ? (72 + ic) : (9 + ic));
        const char* src = btb + (size_t)nks * 16384;
        char* dst = (char*)&bsm[buf ^ 1][0] + tid * 16;
        __builtin_amdgcn_global_load_lds(AS1C(src), AS3(dst), 16, 0, 0);
        __builtin_amdgcn_global_load_lds(AS1C(src + 4096), AS3(dst + 4096), 16, 0, 0);
      }
      // B fragments (lane: out col = l&15, k = (l>>4)*8+j)
      Hfrag bf[4];
#pragma unroll
      for (int n = 0; n < 4; ++n)
        bf[n].v = *(const h8*)(&bsm[buf][(colB + n * 16) * 32 + lg * 8]);
      // A fragments
      Hfrag af[4];
      if (it < 8) {
        const float t = -1.0f + 0.25f * (float)(it + 1);
        const _Float16 c1 = (_Float16)(1.0f + t);
        const _Float16 c2 = (_Float16)(1.0f - t);
        h2 hc1; hc1[0] = c1; hc1[1] = c1;
        h2 hc2; hc2[0] = c2; hc2[1] = c2;
        h2 hz;  hz[0] = (_Float16)0.0f; hz[1] = (_Float16)0.0f;
#pragma unroll
        for (int m = 0; m < 4; ++m) {
#pragma unroll
          for (int q = 0; q < 4; ++q) {
            h2 xv = xn[m].p[q];
            h2 u = hc1 - xv;              // 1 - (xn - t)
            h2 w = hc2 + xv;              // 1 + (xn - t)
            af[m].p[q] = __builtin_elementwise_max(__builtin_elementwise_min(u, w), hz);
          }
        }
#pragma unroll
        for (int m = 0; m < 4; ++m)
#pragma unroll
          for (int n = 0; n < 4; ++n)
            accS[m][n] = __builtin_amdgcn_mfma_f32_16x16x32_f16(af[m].v, bf[n].v, accS[m][n], 0, 0, 0);
      } else {
#pragma unroll
        for (int m = 0; m < 4; ++m) af[m] = xn[m];   // base step: A = xn
#pragma unroll
        for (int m = 0; m < 4; ++m)
#pragma unroll
          for (int n = 0; n < 4; ++n)
            accB[m][n] = __builtin_amdgcn_mfma_f32_16x16x32_f16(af[m].v, bf[n].v, accB[m][n], 0, 0, 0);
        if (ic < 7) {                    // prefetch next ichunk's x (drains at barrier)
          const int ib = (ic + 1) * 32 + lg * 8;
#pragma unroll
          for (int m = 0; m < 4; ++m) {
            const float* px = x + (size_t)(rowA + m * 16) * 256 + ib;
            xa[m] = *(const f4*)px; xb[m] = *(const f4*)(px + 4);
          }
          mn0 = *(const f4*)(minv + ib);  mn1 = *(const f4*)(minv + ib + 4);
          sc0 = *(const f4*)(scalev + ib); sc1 = *(const f4*)(scalev + ib + 4);
        }
      }
      __syncthreads();   // drains global_load_lds (vmcnt) + guards LDS buffer reuse
      buf ^= 1;
    }
  }

  // epilogue: out = silu(accB*bs + bsh) + accS*ss + ssh   (C layout: col=l&15, row=(l>>4)*4+r)
#pragma unroll
  for (int n = 0; n < 4; ++n) {
    const int col = nt * 128 + colB + n * 16;
    const float vbs = bscv[col], vbh = bshv[col];
    const float vss = sscv[col], vsh = sshv[col];
#pragma unroll
    for (int m = 0; m < 4; ++m) {
      const int row0 = mt * 128 + wm * 64 + m * 16 + lg * 4;
#pragma unroll
      for (int r = 0; r < 4; ++r) {
        const float zb = accB[m][n][r] * vbs + vbh;
        const float si = zb / (1.0f + __expf(-zb));
        const float val = si + accS[m][n][r] * vss + vsh;
        out[(size_t)(row0 + r) * 256 + col] = val;
      }
    }
  }
}

extern "C" void kernel_launch(void* const* d_in, const int* in_sizes, int n_in,
                              void* d_out, int out_size, void* d_ws, size_t ws_size,
                              hipStream_t stream) {
  const float* x        = (const float*)d_in[0];
  const float* base_w   = (const float*)d_in[1];
  const float* spline_w = (const float*)d_in[2];
  const float* spline_s = (const float*)d_in[3];
  const float* g1 = (const float*)d_in[4];
  const float* b1 = (const float*)d_in[5];
  const float* m1 = (const float*)d_in[6];
  const float* v1 = (const float*)d_in[7];
  const float* g2 = (const float*)d_in[8];
  const float* b2 = (const float*)d_in[9];
  const float* m2 = (const float*)d_in[10];
  const float* v2 = (const float*)d_in[11];
  float* out = (float*)d_out;
  char* ws = (char*)d_ws;

  float* pmin   = (float*)(ws + WS_PMIN);
  float* pmax   = (float*)(ws + WS_PMAX);
  _Float16* Bt  = (_Float16*)(ws + WS_BT);
  float* minv   = (float*)(ws + WS_MINV);
  float* scalev = (float*)(ws + WS_SCALEV);
  float* rangev = (float*)(ws + WS_RANGEV);
  float* bscv   = (float*)(ws + WS_BSC);
  float* bshv   = (float*)(ws + WS_BSH);
  float* sscv   = (float*)(ws + WS_SSC);
  float* sshv   = (float*)(ws + WS_SSH);

  kan_minmax<<<256, 256, 0, stream>>>(x, pmin, pmax);
  kan_finalize<<<1, 256, 0, stream>>>(pmin, pmax, base_w, g1, b1, m1, v1, g2, b2, m2, v2,
                                      minv, scalev, rangev, bscv, bshv, sscv, sshv);
  kan_buildw<<<640, 256, 0, stream>>>(spline_w, spline_s, base_w, rangev, Bt);
  kan_gemm<<<512, 256, 0, stream>>>(x, Bt, minv, scalev, bscv, bshv, sscv, sshv, out);
}

// Round 2
// 168.001 us; speedup vs baseline: 1.0795x; 1.0795x over previous
//
#include <hip/hip_runtime.h>
#include <stdint.h>
#include <stddef.h>

typedef _Float16 h2 __attribute__((ext_vector_type(2)));
typedef _Float16 h8 __attribute__((ext_vector_type(8)));
typedef float f4 __attribute__((ext_vector_type(4)));

union Hfrag { h2 p[4]; h8 v; };

// ---------------- workspace layout (bytes) ----------------
// pmin/pmax (K1 partials) are dead after K2; Bt (built in K3) overlays them.
#define WS_PMIN   0               // f32 [512][256] = 512 KB
#define WS_PMAX   524288          // f32 [512][256] = 512 KB
#define WS_BT     0               // f16 [80 ks][2 half][128 o][32 kk] = 1,310,720 B
#define WS_SMALL  1310720
#define WS_MINV   (WS_SMALL + 0)
#define WS_SCALEV (WS_SMALL + 1024)
#define WS_BSC    (WS_SMALL + 2048)
#define WS_BSH    (WS_SMALL + 3072)
#define WS_SSC    (WS_SMALL + 4096)
#define WS_SSH    (WS_SMALL + 5120)

// ---------------- K1: per-feature min/max partials ----------------
// 512 blocks x 256 threads; block b covers rows b*64..b*64+63.
// thread = (rg = t>>6, fq = t&63): features fq*4..fq*4+3 (f4 loads), 16 rows.
__global__ __launch_bounds__(256) void kan_minmax(const float* __restrict__ x,
                                                  float* __restrict__ pmin,
                                                  float* __restrict__ pmax) {
  __shared__ f4 smn[4][64], smx[4][64];
  const int b = blockIdx.x, t = threadIdx.x;
  const int fq = t & 63, rg = t >> 6;
  const float* p = x + (size_t)b * 64 * 256 + (size_t)rg * 16 * 256 + fq * 4;
  f4 mn = (f4)(3.402823466e38f), mx = (f4)(-3.402823466e38f);
#pragma unroll
  for (int j = 0; j < 16; ++j) {
    f4 v = *(const f4*)(p + (size_t)j * 256);
    mn = __builtin_elementwise_min(mn, v);
    mx = __builtin_elementwise_max(mx, v);
  }
  smn[rg][fq] = mn; smx[rg][fq] = mx;
  __syncthreads();
  if (rg == 0) {
#pragma unroll
    for (int g = 1; g < 4; ++g) {
      mn = __builtin_elementwise_min(mn, smn[g][fq]);
      mx = __builtin_elementwise_max(mx, smx[g][fq]);
    }
    *(f4*)(pmin + (size_t)b * 256 + fq * 4) = mn;
    *(f4*)(pmax + (size_t)b * 256 + fq * 4) = mx;
  }
}

// ---------------- K2: finalize minmax + BN constants ----------------
// 4 blocks x 256 threads; block bd covers features bd*64..bd*64+63.
// thread = (pg = t>>6, o-lane = t&63): reduce partials pg*128..pg*128+127.
__global__ __launch_bounds__(256) void kan_finalize(
    const float* __restrict__ pmin, const float* __restrict__ pmax,
    const float* __restrict__ g1, const float* __restrict__ b1,
    const float* __restrict__ m1, const float* __restrict__ v1,
    const float* __restrict__ g2, const float* __restrict__ b2,
    const float* __restrict__ m2, const float* __restrict__ v2,
    float* __restrict__ minv, float* __restrict__ scalev,
    float* __restrict__ bscv, float* __restrict__ bshv,
    float* __restrict__ sscv, float* __restrict__ sshv) {
  __shared__ float smn[4][64], smx[4][64];
  const int t = threadIdx.x;
  const int ol = t & 63, pg = t >> 6;
  const int o = blockIdx.x * 64 + ol;
  float mn = 3.402823466e38f, mx = -3.402823466e38f;
  for (int p = pg * 128; p < pg * 128 + 128; ++p) {
    mn = fminf(mn, pmin[(size_t)p * 256 + o]);
    mx = fmaxf(mx, pmax[(size_t)p * 256 + o]);
  }
  smn[pg][ol] = mn; smx[pg][ol] = mx;
  __syncthreads();
  if (pg == 0) {
#pragma unroll
    for (int g = 1; g < 4; ++g) {
      mn = fminf(mn, smn[g][ol]);
      mx = fmaxf(mx, smx[g][ol]);
    }
    minv[o] = mn;
    scalev[o] = 1.0f / (mx - mn + 1e-7f);
    const float bs = g1[o] / sqrtf(v1[o] + 1e-3f);
    bscv[o] = bs;
    bshv[o] = b1[o] - m1[o] * bs;
    const float ss = g2[o] / sqrtf(v2[o] + 1e-3f);
    sscv[o] = ss;
    sshv[o] = b2[o] - m2[o] * ss;
  }
}

// ---------------- K3: build f16 weight matrix Bt ----------------
// Bt flat index f = ((ks*2 + half)*128 + o)*32 + kk   (halves)
// ks<72: spline, k = ks>>3 + 1 is NOT right -- mapping: knot k = ks>>3, i = (ks&7)*32+kk
//        val = sw[o,i,k]*ss[o,i]   (knot 0 chunks ks 0..7 are never read: basis_0 == 0)
// ks>=72: base, i = (ks-72)*32+kk; val = Wb[i,o]   (A will be f16(x))
__global__ __launch_bounds__(256) void kan_buildw(
    const float* __restrict__ spline_w, const float* __restrict__ spline_s,
    const float* __restrict__ base_w, _Float16* __restrict__ Bt) {
  const int gid = blockIdx.x * 256 + threadIdx.x;  // 640 blocks
  const int f = gid * 4;
  const int ks = f >> 13;
  const int rem = f & 8191;
  const int half = rem >> 12;
  const int rem2 = rem & 4095;
  const int o = rem2 >> 5;
  const int kk = rem2 & 31;
  const int og = half * 128 + o;
  float v[4];
  if (ks < 72) {
    const int k = ks >> 3;
    const int i0 = ((ks & 7) << 5) + kk;
#pragma unroll
    for (int j = 0; j < 4; ++j) {
      const int i = i0 + j;
      v[j] = spline_w[(size_t)(og * 256 + i) * 9 + k] * spline_s[og * 256 + i];
    }
  } else {
    const int i0 = (ks - 72) * 32 + kk;
#pragma unroll
    for (int j = 0; j < 4; ++j) {
      const int i = i0 + j;
      v[j] = base_w[(size_t)i * 256 + og];
    }
  }
  union { _Float16 h[4]; uint2 u; } pk;
#pragma unroll
  for (int j = 0; j < 4; ++j) pk.h[j] = (_Float16)v[j];
  *(uint2*)(Bt + f) = pk.u;
}

// ---------------- K4: fused dual GEMM + BN + SiLU (no LDS, no barriers) ----------------
// 128x128 output tile, 4 waves (2x2), 16x16x32 f16 MFMA.
// A (spline basis / f16(x)) generated in registers; B fragments loaded straight
// from L2-resident Bt into registers (coalesced dwordx4) -- waves free-run.
__global__ __launch_bounds__(256, 2) void kan_gemm(
    const float* __restrict__ x, const _Float16* __restrict__ Bt,
    const float* __restrict__ minv, const float* __restrict__ scalev,
    const float* __restrict__ bscv, const float* __restrict__ bshv,
    const float* __restrict__ sscv, const float* __restrict__ sshv,
    float* __restrict__ out) {
  const int tid = threadIdx.x;
  const int lane = tid & 63;
  const int wv = tid >> 6;
  const int wm = wv >> 1, wn = wv & 1;
  const int lr = lane & 15, lg = lane >> 4;
  const int mt = blockIdx.x & 255, nt = blockIdx.x >> 8;  // bid,bid+256 share XCD -> x L2 reuse

  const int rowA = mt * 128 + wm * 64 + lr;   // + 16*m
  const int colB = wn * 64 + lr;              // local out col; + 16*n, global +nt*128

  f4 accS[4][4], accB[4][4];
#pragma unroll
  for (int m = 0; m < 4; ++m)
#pragma unroll
    for (int n = 0; n < 4; ++n) { accS[m][n] = (f4)0.0f; accB[m][n] = (f4)0.0f; }

  // per-lane B base: chunk ks at + ks*16384; fragment n at + n*1024 (imm offset)
  const char* btbase = (const char*)Bt + (size_t)nt * 8192 + (size_t)colB * 64 + (size_t)lg * 16;

  f4 xa[4], xb[4], mn0, mn1, sc0, sc1;

  { // load x fragment regs for ic=0 (+ per-feature min/scale)
    const int ib = lg * 8;
#pragma unroll
    for (int m = 0; m < 4; ++m) {
      const float* px = x + (size_t)(rowA + m * 16) * 256 + ib;
      xa[m] = *(const f4*)px; xb[m] = *(const f4*)(px + 4);
    }
    mn0 = *(const f4*)(minv + ib);  mn1 = *(const f4*)(minv + ib + 4);
    sc0 = *(const f4*)(scalev + ib); sc1 = *(const f4*)(scalev + ib + 4);
  }

#pragma unroll 1
  for (int ic = 0; ic < 8; ++ic) {
    // xn = (x - min) * scale, packed f16 pairs (A-fragment layout)
    Hfrag xn[4];
#pragma unroll
    for (int m = 0; m < 4; ++m) {
      f4 na = (xa[m] - mn0) * sc0;
      f4 nb = (xb[m] - mn1) * sc1;
      xn[m].p[0][0] = (_Float16)na.x; xn[m].p[0][1] = (_Float16)na.y;
      xn[m].p[1][0] = (_Float16)na.z; xn[m].p[1][1] = (_Float16)na.w;
      xn[m].p[2][0] = (_Float16)nb.x; xn[m].p[2][1] = (_Float16)nb.y;
      xn[m].p[3][0] = (_Float16)nb.z; xn[m].p[3][1] = (_Float16)nb.w;
    }
#pragma unroll
    for (int it = 0; it < 9; ++it) {   // it 0..7: knots 1..8 ; it 8: base GEMM step
      const int cks = (it < 8) ? ((it + 1) * 8 + ic) : (72 + ic);
      const char* bp = btbase + (size_t)cks * 16384;
      Hfrag bf[4];
#pragma unroll
      for (int n = 0; n < 4; ++n)
        bf[n].v = *(const h8*)(bp + n * 1024);
      if (it < 8) {
        const float t = -1.0f + 0.25f * (float)(it + 1);
        const _Float16 c1 = (_Float16)(1.0f + t);
        const _Float16 c2 = (_Float16)(1.0f - t);
        h2 hc1; hc1[0] = c1; hc1[1] = c1;
        h2 hc2; hc2[0] = c2; hc2[1] = c2;
        h2 hz;  hz[0] = (_Float16)0.0f; hz[1] = (_Float16)0.0f;
        Hfrag af[4];
#pragma unroll
        for (int m = 0; m < 4; ++m) {
#pragma unroll
          for (int q = 0; q < 4; ++q) {
            h2 xv = xn[m].p[q];
            h2 u = hc1 - xv;              // 1 - (xn - t)
            h2 w = hc2 + xv;              // 1 + (xn - t)
            af[m].p[q] = __builtin_elementwise_max(__builtin_elementwise_min(u, w), hz);
          }
        }
#pragma unroll
        for (int m = 0; m < 4; ++m)
#pragma unroll
          for (int n = 0; n < 4; ++n)
            accS[m][n] = __builtin_amdgcn_mfma_f32_16x16x32_f16(af[m].v, bf[n].v, accS[m][n], 0, 0, 0);
      } else {
        // base step: A = f16(x) verbatim
        Hfrag af[4];
#pragma unroll
        for (int m = 0; m < 4; ++m) {
          af[m].p[0][0] = (_Float16)xa[m].x; af[m].p[0][1] = (_Float16)xa[m].y;
          af[m].p[1][0] = (_Float16)xa[m].z; af[m].p[1][1] = (_Float16)xa[m].w;
          af[m].p[2][0] = (_Float16)xb[m].x; af[m].p[2][1] = (_Float16)xb[m].y;
          af[m].p[3][0] = (_Float16)xb[m].z; af[m].p[3][1] = (_Float16)xb[m].w;
        }
#pragma unroll
        for (int m = 0; m < 4; ++m)
#pragma unroll
          for (int n = 0; n < 4; ++n)
            accB[m][n] = __builtin_amdgcn_mfma_f32_16x16x32_f16(af[m].v, bf[n].v, accB[m][n], 0, 0, 0);
        if (ic < 7) {                    // prefetch next ichunk's x / min / scale
          const int ib = (ic + 1) * 32 + lg * 8;
#pragma unroll
          for (int m = 0; m < 4; ++m) {
            const float* px = x + (size_t)(rowA + m * 16) * 256 + ib;
            xa[m] = *(const f4*)px; xb[m] = *(const f4*)(px + 4);
          }
          mn0 = *(const f4*)(minv + ib);  mn1 = *(const f4*)(minv + ib + 4);
          sc0 = *(const f4*)(scalev + ib); sc1 = *(const f4*)(scalev + ib + 4);
        }
      }
    }
  }

  // epilogue: out = silu(accB*bs + bsh) + accS*ss + ssh   (C layout: col=l&15, row=(l>>4)*4+r)
#pragma unroll
  for (int n = 0; n < 4; ++n) {
    const int col = nt * 128 + colB + n * 16;
    const float vbs = bscv[col], vbh = bshv[col];
    const float vss = sscv[col], vsh = sshv[col];
#pragma unroll
    for (int m = 0; m < 4; ++m) {
      const int row0 = mt * 128 + wm * 64 + m * 16 + lg * 4;
#pragma unroll
      for (int r = 0; r < 4; ++r) {
        const float zb = accB[m][n][r] * vbs + vbh;
        const float si = zb / (1.0f + __expf(-zb));
        const float val = si + accS[m][n][r] * vss + vsh;
        out[(size_t)(row0 + r) * 256 + col] = val;
      }
    }
  }
}

extern "C" void kernel_launch(void* const* d_in, const int* in_sizes, int n_in,
                              void* d_out, int out_size, void* d_ws, size_t ws_size,
                              hipStream_t stream) {
  const float* x        = (const float*)d_in[0];
  const float* base_w   = (const float*)d_in[1];
  const float* spline_w = (const float*)d_in[2];
  const float* spline_s = (const float*)d_in[3];
  const float* g1 = (const float*)d_in[4];
  const float* b1 = (const float*)d_in[5];
  const float* m1 = (const float*)d_in[6];
  const float* v1 = (const float*)d_in[7];
  const float* g2 = (const float*)d_in[8];
  const float* b2 = (const float*)d_in[9];
  const float* m2 = (const float*)d_in[10];
  const float* v2 = (const float*)d_in[11];
  float* out = (float*)d_out;
  char* ws = (char*)d_ws;

  float* pmin   = (float*)(ws + WS_PMIN);
  float* pmax   = (float*)(ws + WS_PMAX);
  _Float16* Bt  = (_Float16*)(ws + WS_BT);
  float* minv   = (float*)(ws + WS_MINV);
  float* scalev = (float*)(ws + WS_SCALEV);
  float* bscv   = (float*)(ws + WS_BSC);
  float* bshv   = (float*)(ws + WS_BSH);
  float* sscv   = (float*)(ws + WS_SSC);
  float* sshv   = (float*)(ws + WS_SSH);

  kan_minmax<<<512, 256, 0, stream>>>(x, pmin, pmax);
  kan_finalize<<<4, 256, 0, stream>>>(pmin, pmax, g1, b1, m1, v1, g2, b2, m2, v2,
                                      minv, scalev, bscv, bshv, sscv, sshv);
  kan_buildw<<<640, 256, 0, stream>>>(spline_w, spline_s, base_w, Bt);
  kan_gemm<<<512, 256, 0, stream>>>(x, Bt, minv, scalev, bscv, bshv, sscv, sshv, out);
}